// Round 4
// baseline (2447.356 us; speedup 1.0000x reference)
//
#include <hip/hip_runtime.h>

typedef short  short8   __attribute__((ext_vector_type(8)));
typedef float  floatx4  __attribute__((ext_vector_type(4)));
typedef unsigned int uintx2 __attribute__((ext_vector_type(2)));

#define LOG2E_X2 2.8853900817779268f

__device__ __forceinline__ float tanh_fast(float a) {
    float e = __builtin_amdgcn_exp2f(a * LOG2E_X2);
    return 1.0f - 2.0f * __builtin_amdgcn_rcpf(1.0f + e);
}

__device__ __forceinline__ unsigned short bf16rne(float f) {   // setup only
    unsigned u = __float_as_uint(f);
    u += 0x7FFFu + ((u >> 16) & 1u);
    return (unsigned short)(u >> 16);
}

#if __has_builtin(__builtin_amdgcn_cvt_pk_bf16_f32)
__device__ __forceinline__ unsigned pk2(float a, float b) {
    auto r = __builtin_amdgcn_cvt_pk_bf16_f32(a, b);
    unsigned u; __builtin_memcpy(&u, &r, 4);
    return u;
}
#else
__device__ __forceinline__ unsigned pk2(float a, float b) {
    unsigned ua = __float_as_uint(a), ub = __float_as_uint(b);
    ua += 0x7FFFu + ((ua >> 16) & 1u);
    ub += 0x7FFFu + ((ub >> 16) & 1u);
    return __builtin_amdgcn_perm(ub, ua, 0x07060302);
}
#endif

// Round 4: wave-private trajectories. 512 blocks x 256 thr; wave owns 16 rows
// for all 64 evals. W2 frags (all 64 d) in registers; W1 frags (all 256
// hidden) in LDS (shared, built once); h round-trips a wave-private 2x1KB
// ping-pong in an 8-chunk pipeline. ZERO barriers in the eval loop.
__global__ __launch_bounds__(256, 2) void ode_wp(
    const float* __restrict__ s_in,  const float* __restrict__ t_in,
    const float* __restrict__ phi_in,const float* __restrict__ bfr_in,
    const float* __restrict__ w1_in, const float* __restrict__ b1_in,
    const float* __restrict__ w2_in, const float* __restrict__ b2_in,
    float* __restrict__ out)
{
    const int tid  = threadIdx.x;
    const int wv   = tid >> 6;
    const int lane = tid & 63;
    const int l15  = lane & 15;
    const int q    = lane >> 4;

    const int g     = blockIdx.x * 4 + wv;   // wave id 0..2047
    const int rowg0 = g * 16;                // global row base (16 rows/wave)
    const int sb    = rowg0 >> 11;           // (s*8+b)
    const int nloc  = rowg0 & 2047;          // node base within (s,b)

    __shared__ short w1lds[48 * 512];        // 48 frags x 1KB (A-frag layout)
    __shared__ float b1s[256];
    __shared__ short bufs[4][2][512];        // per-wave 2x1KB ping-pong
    __shared__ float dls[8];

    // ---- build W1 A-frags in LDS (wave wv builds frags wv*12..+12) ----
    // frag fid = ht*3+kk: A[m=l15 -> hidden=ht*16+l15][k=q*8+j -> feat=kk*32+q*8+j]
#pragma unroll
    for (int f = 0; f < 12; ++f) {
        int fid = wv * 12 + f;
        int ht = fid / 3, kk = fid % 3;
        short8 fr;
#pragma unroll
        for (int j = 0; j < 8; ++j)
            fr[j] = (short)bf16rne(w1_in[(kk * 32 + q * 8 + j) * 256 + ht * 16 + l15]);
        *(short8*)&w1lds[fid * 512 + lane * 8] = fr;
    }
    if (tid < 64) *(floatx4*)&b1s[tid * 4] = *(const floatx4*)(b1_in + tid * 4);
    {
        int sbb = (blockIdx.x * 64) >> 11;   // block-level sb (same for all 4 waves)
        if (tid < 8) dls[tid] = t_in[sbb * 9 + tid + 1] - t_in[sbb * 9 + tid];
    }

    // ---- W2 A-frags in registers: frag(dt,kk): A[m=l15 -> d=dt*16+l15][k -> hid=kk*32+q*8+j]
    short8 w2f[4][8];
#pragma unroll
    for (int dt = 0; dt < 4; ++dt)
#pragma unroll
        for (int kk = 0; kk < 8; ++kk) {
            short8 fr;
#pragma unroll
            for (int j = 0; j < 8; ++j)
                fr[j] = (short)bf16rne(w2_in[(kk * 32 + q * 8 + j) * 64 + dt * 16 + l15]);
            w2f[dt][kk] = fr;
        }

    // ---- static Phi B-frag (features 64..95): B[k=q*8+j][n=l15] ----
    short8 xbp;
#pragma unroll
    for (int j = 0; j < 8; ++j)
        xbp[j] = (short)bf16rne(phi_in[(rowg0 + l15) * 32 + q * 8 + j]);

    // ---- RK4 state: lane holds x[row=l15][d=dt*16+q*4+r] ----
    floatx4 xv[4], kacc[4], fbv[4];
#pragma unroll
    for (int dt = 0; dt < 4; ++dt) {
        int off = (rowg0 + l15) * 64 + dt * 16 + q * 4;
        xv[dt]  = *(const floatx4*)(s_in + off);
        fbv[dt] = *(const floatx4*)(b2_in + dt * 16 + q * 4)
                + *(const floatx4*)(bfr_in + off);
    }

    __syncthreads();   // the ONLY barrier

    const int qh = q >> 1, ql = q & 1;

#pragma unroll 1
    for (int blk = 0; blk < 8; ++blk) {
        const float dlt = dls[blk];
#pragma unroll 1
        for (int stp = 0; stp < 2; ++stp) {
#pragma unroll 1
            for (int sub = 0; sub < 4; ++sub) {
                // ---- pack state into x B-frags (wave-private LDS round-trip) ----
#pragma unroll
                for (int dt = 0; dt < 4; ++dt) {
                    uintx2 P = { pk2(xv[dt][0], xv[dt][1]), pk2(xv[dt][2], xv[dt][3]) };
                    int qt = 2 * (dt & 1) + qh;
                    *(uintx2*)&bufs[wv][dt >> 1][(qt * 16 + l15) * 8 + ql * 4] = P;
                }
                short8 xb0 = *(const short8*)&bufs[wv][0][lane * 8];
                short8 xb1 = *(const short8*)&bufs[wv][1][lane * 8];

                floatx4 acc2[4];
#pragma unroll
                for (int dt = 0; dt < 4; ++dt) acc2[dt] = fbv[dt];

                // ---- 8-chunk pipeline: GEMM1(2 tiles)+tanh -> buf -> GEMM2 partial ----
#pragma unroll
                for (int k = 0; k < 8; ++k) {
#pragma unroll
                    for (int c = 0; c < 2; ++c) {
                        int ht = 2 * k + c;
                        floatx4 acc = *(const floatx4*)&b1s[ht * 16 + q * 4];
                        acc = __builtin_amdgcn_mfma_f32_16x16x32_bf16(
                            *(const short8*)&w1lds[(ht * 3 + 0) * 512 + lane * 8], xb0, acc, 0, 0, 0);
                        acc = __builtin_amdgcn_mfma_f32_16x16x32_bf16(
                            *(const short8*)&w1lds[(ht * 3 + 1) * 512 + lane * 8], xb1, acc, 0, 0, 0);
                        acc = __builtin_amdgcn_mfma_f32_16x16x32_bf16(
                            *(const short8*)&w1lds[(ht * 3 + 2) * 512 + lane * 8], xbp, acc, 0, 0, 0);
                        uintx2 hp = { pk2(tanh_fast(acc[0]), tanh_fast(acc[1])),
                                      pk2(tanh_fast(acc[2]), tanh_fast(acc[3])) };
                        int qt = 2 * (ht & 1) + qh;
                        *(uintx2*)&bufs[wv][k & 1][(qt * 16 + l15) * 8 + ql * 4] = hp;
                    }
                    short8 hb = *(const short8*)&bufs[wv][k & 1][lane * 8];
#pragma unroll
                    for (int dt = 0; dt < 4; ++dt)
                        acc2[dt] = __builtin_amdgcn_mfma_f32_16x16x32_bf16(
                            w2f[dt][k], hb, acc2[dt], 0, 0, 0);
                }

                // ---- RK4 epilogue (registers only) ----
#pragma unroll
                for (int dt = 0; dt < 4; ++dt) {
                    floatx4 kv = acc2[dt] * dlt;
                    if (sub == 0)      { kacc[dt] = kv;            xv[dt] += 0.0f; }
                    else if (sub == 1) { kacc[dt] += 2.0f * kv; }
                    else if (sub == 2) { kacc[dt] += 2.0f * kv; }
                    else               { }
                    // x at next eval point (xe) replaces the packed state:
                    // keep xe in xv-adjacent temp? We fold: store eval point into xv? No:
                    // xv must stay at block start until sub==3. Use separate register:
                }
                // Recompute eval points without disturbing xv until sub==3:
                // (done explicitly below to keep live set small)
                if (sub < 3) {
#pragma unroll
                    for (int dt = 0; dt < 4; ++dt) {
                        floatx4 kv = acc2[dt] * dlt;
                        float cf = (sub == 2) ? 0.5f : 0.25f;
                        floatx4 xe = xv[dt] + cf * kv;
                        // stash eval point for next pack: overwrite a dedicated reg set
                        // -> simplest: write packed form directly now
                        uintx2 P = { pk2(xe[0], xe[1]), pk2(xe[2], xe[3]) };
                        int qt = 2 * (dt & 1) + qh;
                        // pre-stage next eval's x-frags right here (replaces top-of-loop
                        // pack on next iteration -- but loop still packs xv; so instead
                        // we keep xv as THE eval point: see below)
                        (void)P; (void)qt;
                    }
                }
                // NOTE: to keep the loop structure simple and registers tight we
                // instead maintain: xv = current eval point, xbase/kacc carry RK4.
                // Handled via the transformation below.
#pragma unroll
                for (int dt = 0; dt < 4; ++dt) {
                    floatx4 kv = acc2[dt] * dlt;
                    if (sub == 0) {
                        // xv was x0. kacc holds k1 after this; xv becomes x0+0.25 k1.
                        // restore base later: x0 = xv - 0.25*k1
                        kacc[dt] = kv;
                        xv[dt] = xv[dt] + 0.25f * kv;
                    } else if (sub == 1) {
                        // xv = x0+0.25 k1 ; base x0 = xv - 0.25*kacc(=k1)
                        floatx4 x0 = xv[dt] - 0.25f * kacc[dt];
                        kacc[dt] += 2.0f * kv;
                        xv[dt] = x0 + 0.25f * kv;
                    } else if (sub == 2) {
                        floatx4 x0 = xv[dt] - 0.25f * kacc[dt] + 0.5f * kacc[dt] * 0.0f;
                        // careful: at sub==2 entry, xv = x0 + 0.25*k2, kacc = k1+2k2.
                        // x0 = xv - 0.25*(kacc - k1 ... ) -- not recoverable from kacc alone.
                        // (handled by restructure below; this branch is dead)
                        (void)x0;
                    }
                }
                // --- the arithmetic above for sub>=1 can't recover x0 from kacc ---
                // Final correct implementation (overwrites any partial updates):
                // We therefore keep an explicit base copy per block-step. Registers:
                // xb4[4] lives only within the 8-eval stp/sub scope.
                (void)0;
            }
        }
        // placeholder store (replaced below)
    }
    // NOTE: restructured clean version follows in ode_wp2; this kernel is unused.
}

// ---------------- CLEAN IMPLEMENTATION (used) ----------------
__global__ __launch_bounds__(256, 2) void ode_wp2(
    const float* __restrict__ s_in,  const float* __restrict__ t_in,
    const float* __restrict__ phi_in,const float* __restrict__ bfr_in,
    const float* __restrict__ w1_in, const float* __restrict__ b1_in,
    const float* __restrict__ w2_in, const float* __restrict__ b2_in,
    float* __restrict__ out)
{
    const int tid  = threadIdx.x;
    const int wv   = tid >> 6;
    const int lane = tid & 63;
    const int l15  = lane & 15;
    const int q    = lane >> 4;

    const int g     = blockIdx.x * 4 + wv;
    const int rowg0 = g * 16;
    const int sb    = rowg0 >> 11;
    const int nloc  = rowg0 & 2047;

    __shared__ short w1lds[48 * 512];
    __shared__ float b1s[256];
    __shared__ short bufs[4][2][512];
    __shared__ float dls[8];

#pragma unroll
    for (int f = 0; f < 12; ++f) {
        int fid = wv * 12 + f;
        int ht = fid / 3, kk = fid % 3;
        short8 fr;
#pragma unroll
        for (int j = 0; j < 8; ++j)
            fr[j] = (short)bf16rne(w1_in[(kk * 32 + q * 8 + j) * 256 + ht * 16 + l15]);
        *(short8*)&w1lds[fid * 512 + lane * 8] = fr;
    }
    if (tid < 64) *(floatx4*)&b1s[tid * 4] = *(const floatx4*)(b1_in + tid * 4);
    {
        int sbb = (blockIdx.x * 64) >> 11;
        if (tid < 8) dls[tid] = t_in[sbb * 9 + tid + 1] - t_in[sbb * 9 + tid];
    }

    short8 w2f[4][8];
#pragma unroll
    for (int dt = 0; dt < 4; ++dt)
#pragma unroll
        for (int kk = 0; kk < 8; ++kk) {
            short8 fr;
#pragma unroll
            for (int j = 0; j < 8; ++j)
                fr[j] = (short)bf16rne(w2_in[(kk * 32 + q * 8 + j) * 64 + dt * 16 + l15]);
            w2f[dt][kk] = fr;
        }

    short8 xbp;
#pragma unroll
    for (int j = 0; j < 8; ++j)
        xbp[j] = (short)bf16rne(phi_in[(rowg0 + l15) * 32 + q * 8 + j]);

    // xv = RK4 base state x; xe = current MLP eval point; kacc = k-accumulator
    floatx4 xv[4], kacc[4], fbv[4];
#pragma unroll
    for (int dt = 0; dt < 4; ++dt) {
        int off = (rowg0 + l15) * 64 + dt * 16 + q * 4;
        xv[dt]  = *(const floatx4*)(s_in + off);
        fbv[dt] = *(const floatx4*)(b2_in + dt * 16 + q * 4)
                + *(const floatx4*)(bfr_in + off);
    }

    __syncthreads();   // the ONLY barrier

    const int qh = q >> 1, ql = q & 1;

#pragma unroll 1
    for (int blk = 0; blk < 8; ++blk) {
        const float dlt = dls[blk];
#pragma unroll 1
        for (int stp = 0; stp < 2; ++stp) {
            floatx4 xe[4];
#pragma unroll
            for (int dt = 0; dt < 4; ++dt) xe[dt] = xv[dt];
#pragma unroll 1
            for (int sub = 0; sub < 4; ++sub) {
                // ---- pack eval point xe into x B-frags via wave-private LDS ----
#pragma unroll
                for (int dt = 0; dt < 4; ++dt) {
                    uintx2 P = { pk2(xe[dt][0], xe[dt][1]), pk2(xe[dt][2], xe[dt][3]) };
                    int qt = 2 * (dt & 1) + qh;
                    *(uintx2*)&bufs[wv][dt >> 1][(qt * 16 + l15) * 8 + ql * 4] = P;
                }
                short8 xb0 = *(const short8*)&bufs[wv][0][lane * 8];
                short8 xb1 = *(const short8*)&bufs[wv][1][lane * 8];

                floatx4 acc2[4];
#pragma unroll
                for (int dt = 0; dt < 4; ++dt) acc2[dt] = fbv[dt];

#pragma unroll
                for (int k = 0; k < 8; ++k) {
#pragma unroll
                    for (int c = 0; c < 2; ++c) {
                        int ht = 2 * k + c;
                        floatx4 acc = *(const floatx4*)&b1s[ht * 16 + q * 4];
                        acc = __builtin_amdgcn_mfma_f32_16x16x32_bf16(
                            *(const short8*)&w1lds[(ht * 3 + 0) * 512 + lane * 8], xb0, acc, 0, 0, 0);
                        acc = __builtin_amdgcn_mfma_f32_16x16x32_bf16(
                            *(const short8*)&w1lds[(ht * 3 + 1) * 512 + lane * 8], xb1, acc, 0, 0, 0);
                        acc = __builtin_amdgcn_mfma_f32_16x16x32_bf16(
                            *(const short8*)&w1lds[(ht * 3 + 2) * 512 + lane * 8], xbp, acc, 0, 0, 0);
                        uintx2 hp = { pk2(tanh_fast(acc[0]), tanh_fast(acc[1])),
                                      pk2(tanh_fast(acc[2]), tanh_fast(acc[3])) };
                        int qt = 2 * (ht & 1) + qh;
                        *(uintx2*)&bufs[wv][k & 1][(qt * 16 + l15) * 8 + ql * 4] = hp;
                    }
                    short8 hb = *(const short8*)&bufs[wv][k & 1][lane * 8];
#pragma unroll
                    for (int dt = 0; dt < 4; ++dt)
                        acc2[dt] = __builtin_amdgcn_mfma_f32_16x16x32_bf16(
                            w2f[dt][k], hb, acc2[dt], 0, 0, 0);
                }

                // ---- RK4 update: kv = f(xe)*dlt ----
#pragma unroll
                for (int dt = 0; dt < 4; ++dt) {
                    floatx4 kv = acc2[dt] * dlt;
                    if (sub == 0)      { kacc[dt] = kv;           xe[dt] = xv[dt] + 0.25f * kv; }
                    else if (sub == 1) { kacc[dt] += 2.0f * kv;   xe[dt] = xv[dt] + 0.25f * kv; }
                    else if (sub == 2) { kacc[dt] += 2.0f * kv;   xe[dt] = xv[dt] + 0.5f  * kv; }
                    else               { xv[dt] += (kacc[dt] + kv) * (1.0f / 12.0f); }
                }
            }
        }
        const size_t ob = (size_t)(sb * 8 + blk) * 2048 + nloc + l15;
#pragma unroll
        for (int dt = 0; dt < 4; ++dt)
            *(floatx4*)(out + ob * 64 + dt * 16 + q * 4) = xv[dt];
    }
}

extern "C" void kernel_launch(void* const* d_in, const int* in_sizes, int n_in,
                              void* d_out, int out_size, void* d_ws, size_t ws_size,
                              hipStream_t stream) {
    const float* s_in  = (const float*)d_in[0];
    const float* t_in  = (const float*)d_in[1];
    const float* phi   = (const float*)d_in[2];
    const float* bfr   = (const float*)d_in[3];
    const float* w1    = (const float*)d_in[4];
    const float* b1    = (const float*)d_in[5];
    const float* w2    = (const float*)d_in[6];
    const float* b2    = (const float*)d_in[7];
    ode_wp2<<<512, 256, 0, stream>>>(s_in, t_in, phi, bfr, w1, b1, w2, b2, (float*)d_out);
}

// Round 6
// 446.833 us; speedup vs baseline: 5.4771x; 5.4771x over previous
//
#include <hip/hip_runtime.h>

typedef short  short8   __attribute__((ext_vector_type(8)));
typedef float  floatx4  __attribute__((ext_vector_type(4)));
typedef unsigned int uintx2 __attribute__((ext_vector_type(2)));

#define LOG2E_X2 2.8853900817779268f

__device__ __forceinline__ float tanh_fast(float a) {
    float e = __builtin_amdgcn_exp2f(a * LOG2E_X2);
    return 1.0f - 2.0f * __builtin_amdgcn_rcpf(1.0f + e);
}

__device__ __forceinline__ unsigned short bf16rne(float f) {   // setup only
    unsigned u = __float_as_uint(f);
    u += 0x7FFFu + ((u >> 16) & 1u);
    return (unsigned short)(u >> 16);
}

#if __has_builtin(__builtin_amdgcn_cvt_pk_bf16_f32)
__device__ __forceinline__ unsigned pk2(float a, float b) {
    auto r = __builtin_amdgcn_cvt_pk_bf16_f32(a, b);
    unsigned u; __builtin_memcpy(&u, &r, 4);
    return u;
}
#else
__device__ __forceinline__ unsigned pk2(float a, float b) {
    unsigned ua = __float_as_uint(a), ub = __float_as_uint(b);
    ua += 0x7FFFu + ((ua >> 16) & 1u);
    ub += 0x7FFFu + ((ub >> 16) & 1u);
    return __builtin_amdgcn_perm(ub, ua, 0x07060302);
}
#endif

// Round 6: bisect of R5's race. EXACT R1/R3 access sets (GEMM1: wave owns 64
// hidden cols, all rows; GEMM2: every wave reads all 64 Hs rows, owns d-cols
// wv*16..+15; epilogue writes Atile cols wv*16..+15, all rows) — these sets
// passed post-timing validation in R1/R2/R3. Kept from R5: rt-interleaved
// phase bodies. Added: __threadfence_block() before each __syncthreads()
// (defensive lgkmcnt drain). The 2x2 GEMM2 quadrant split is REMOVED (prime
// race suspect).
__global__ __launch_bounds__(256, 2) void ode_r6(
    const float* __restrict__ s_in,  const float* __restrict__ t_in,
    const float* __restrict__ phi_in,const float* __restrict__ bfr_in,
    const float* __restrict__ w1_in, const float* __restrict__ b1_in,
    const float* __restrict__ w2_in, const float* __restrict__ b2_in,
    float* __restrict__ out)
{
    const int tid  = threadIdx.x;
    const int wv   = tid >> 6;
    const int lane = tid & 63;
    const int l15  = lane & 15;
    const int q    = lane >> 4;
    const int wg   = blockIdx.x;
    const int sb   = wg >> 5;
    const int n0   = (wg & 31) << 6;
    const int rowg0 = sb * 2048 + n0;

    __shared__ __align__(16) unsigned short Atile[64][104];  // x(64) || phi(32), bf16
    __shared__ __align__(16) unsigned short Hs[64][264];     // h, bf16
    __shared__ float dls[8];

    const int d0 = wv * 16 + q * 4;    // lane's 4 consecutive d columns (R1 mapping)

    // ---- persistent register fragments ----
    // W1 A-frags: hidden = wv*64 + ht*16 + l15, feat k = kk*32 + q*8 + j
    short8 w1f[4][3];
#pragma unroll
    for (int ht = 0; ht < 4; ++ht)
#pragma unroll
        for (int kk = 0; kk < 3; ++kk) {
            short8 f;
#pragma unroll
            for (int j = 0; j < 8; ++j)
                f[j] = (short)bf16rne(w1_in[(kk * 32 + q * 8 + j) * 256 + wv * 64 + ht * 16 + l15]);
            w1f[ht][kk] = f;
        }
    // W2 A-frags: d = wv*16 + l15, hid k = kk*32 + q*8 + j   (R1 mapping)
    short8 w2f[8];
#pragma unroll
    for (int kk = 0; kk < 8; ++kk) {
        short8 f;
#pragma unroll
        for (int j = 0; j < 8; ++j)
            f[j] = (short)bf16rne(w2_in[(kk * 32 + q * 8 + j) * 64 + wv * 16 + l15]);
        w2f[kk] = f;
    }
    // b1 acc1-seed frags (C-layout: hidden row = q*4+r within ht-tile)
    floatx4 bb[4];
#pragma unroll
    for (int ht = 0; ht < 4; ++ht)
        bb[ht] = *(const floatx4*)(b1_in + (wv * 4 + ht) * 16 + q * 4);

    // RK4 state: lane owns (row = rt*16+l15, d = d0..d0+3), rt = 0..3  (R1 mapping)
    floatx4 xv[4], kacc[4], fbv[4];
    {
        const floatx4 b2v = *(const floatx4*)(b2_in + d0);
#pragma unroll
        for (int rt = 0; rt < 4; ++rt) {
            int off = (rowg0 + rt * 16 + l15) * 64 + d0;
            xv[rt]  = *(const floatx4*)(s_in + off);
            fbv[rt] = b2v + *(const floatx4*)(bfr_in + off);
            uintx2 px = { pk2(xv[rt][0], xv[rt][1]), pk2(xv[rt][2], xv[rt][3]) };
            *(uintx2*)&Atile[rt * 16 + l15][d0] = px;
        }
    }
    // Phi -> Atile cols 64..95
#pragma unroll
    for (int it = 0; it < 2; ++it) {
        int c2 = tid * 2 + it;           // 0..511
        int row = c2 >> 3, cc = c2 & 7;
        floatx4 p = *(const floatx4*)(phi_in + (rowg0 + row) * 32 + cc * 4);
        uintx2 px = { pk2(p[0], p[1]), pk2(p[2], p[3]) };
        *(uintx2*)&Atile[row][64 + cc * 4] = px;
    }
    if (tid < 8) dls[tid] = t_in[sb * 9 + tid + 1] - t_in[sb * 9 + tid];

    __threadfence_block();
    __syncthreads();

#pragma unroll 1
    for (int blk = 0; blk < 8; ++blk) {
        const float dlt = dls[blk];
#pragma unroll 1
        for (int stp = 0; stp < 2; ++stp) {
#pragma unroll 1
            for (int sub = 0; sub < 4; ++sub) {
                __threadfence_block();
                __syncthreads();   // Atile writes visible

                // ---- GEMM1 + tanh, rt-interleaved (wave: hidden wv*64..+63, all rows) ----
#pragma unroll
                for (int rt = 0; rt < 4; ++rt) {
                    short8 xb0 = *(const short8*)&Atile[rt * 16 + l15][q * 8];
                    short8 xb1 = *(const short8*)&Atile[rt * 16 + l15][32 + q * 8];
                    short8 xb2 = *(const short8*)&Atile[rt * 16 + l15][64 + q * 8];
                    floatx4 a1[4];
#pragma unroll
                    for (int ht = 0; ht < 4; ++ht)
                        a1[ht] = __builtin_amdgcn_mfma_f32_16x16x32_bf16(w1f[ht][0], xb0, bb[ht], 0, 0, 0);
#pragma unroll
                    for (int ht = 0; ht < 4; ++ht)
                        a1[ht] = __builtin_amdgcn_mfma_f32_16x16x32_bf16(w1f[ht][1], xb1, a1[ht], 0, 0, 0);
#pragma unroll
                    for (int ht = 0; ht < 4; ++ht)
                        a1[ht] = __builtin_amdgcn_mfma_f32_16x16x32_bf16(w1f[ht][2], xb2, a1[ht], 0, 0, 0);
#pragma unroll
                    for (int ht = 0; ht < 4; ++ht) {
                        uintx2 hp = { pk2(tanh_fast(a1[ht][0]), tanh_fast(a1[ht][1])),
                                      pk2(tanh_fast(a1[ht][2]), tanh_fast(a1[ht][3])) };
                        *(uintx2*)&Hs[rt * 16 + l15][(wv * 4 + ht) * 16 + q * 4] = hp;
                    }
                }
                __threadfence_block();
                __syncthreads();   // Hs visible; Atile reads done

                // ---- GEMM2 + RK4, rt-interleaved (wave: d-cols d0..d0+3 group, ALL rows) ----
#pragma unroll
                for (int rt = 0; rt < 4; ++rt) {
                    floatx4 a2;
                    {
                        short8 hb = *(const short8*)&Hs[rt * 16 + l15][q * 8];
                        a2 = __builtin_amdgcn_mfma_f32_16x16x32_bf16(w2f[0], hb, fbv[rt], 0, 0, 0);
                    }
#pragma unroll
                    for (int kk = 1; kk < 8; ++kk) {
                        short8 hb = *(const short8*)&Hs[rt * 16 + l15][kk * 32 + q * 8];
                        a2 = __builtin_amdgcn_mfma_f32_16x16x32_bf16(w2f[kk], hb, a2, 0, 0, 0);
                    }
                    floatx4 kv = a2 * dlt;
                    floatx4 xe;
                    if (sub == 0)      { kacc[rt] = kv;           xe = xv[rt] + 0.25f * kv; }
                    else if (sub == 1) { kacc[rt] += 2.0f * kv;   xe = xv[rt] + 0.25f * kv; }
                    else if (sub == 2) { kacc[rt] += 2.0f * kv;   xe = xv[rt] + 0.5f  * kv; }
                    else { xv[rt] += (kacc[rt] + kv) * (1.0f / 12.0f); xe = xv[rt]; }
                    uintx2 px = { pk2(xe[0], xe[1]), pk2(xe[2], xe[3]) };
                    *(uintx2*)&Atile[rt * 16 + l15][d0] = px;
                }
            }
        }
        // ---- emit x after this block step ----
        const int ob = (sb * 8 + blk) * 2048 + n0;
#pragma unroll
        for (int rt = 0; rt < 4; ++rt)
            *(floatx4*)(out + (size_t)(ob + rt * 16 + l15) * 64 + d0) = xv[rt];
    }
}

extern "C" void kernel_launch(void* const* d_in, const int* in_sizes, int n_in,
                              void* d_out, int out_size, void* d_ws, size_t ws_size,
                              hipStream_t stream) {
    const float* s_in  = (const float*)d_in[0];
    const float* t_in  = (const float*)d_in[1];
    const float* phi   = (const float*)d_in[2];
    const float* bfr   = (const float*)d_in[3];
    const float* w1    = (const float*)d_in[4];
    const float* b1    = (const float*)d_in[5];
    const float* w2    = (const float*)d_in[6];
    const float* b2    = (const float*)d_in[7];
    ode_r6<<<512, 256, 0, stream>>>(s_in, t_in, phi, bfr, w1, b1, w2, b2, (float*)d_out);
}